// Round 2
// baseline (198.087 us; speedup 1.0000x reference)
//
#include <hip/hip_runtime.h>

// Problem constants (EdgeAwareMultiHeadAttention)
constexpr int Bb   = 4;
constexpr int Nn   = 256;
constexpr int HID  = 256;
constexpr int Ee   = 64;
constexpr int Hh   = 4;
constexpr int OUTc = 128;   // HID/2
constexpr int Dd   = 32;    // OUT/H
constexpr int AGG  = 260;   // H*(2D+1)

constexpr int MT    = 32;   // m-tile rows
constexpr int TPB   = 2;    // tiles per block (64 m-rows per block)
constexpr int NTP   = Nn / (MT * TPB);   // 4 tile-pairs per bn
constexpr int A_LD  = 72;   // bf16 row stride for A tile
constexpr int K_LD  = 132;  // fp32 row stride for K tile (pad 128->132)
constexpr int REC   = 264;  // ws record stride (260 padded to 16B multiple)

typedef __attribute__((ext_vector_type(8))) short short8;
typedef __attribute__((ext_vector_type(4))) float floatx4;

__device__ __forceinline__ unsigned short f2bf(float f) {
    union { float f; unsigned u; } x; x.f = f;
    unsigned r = x.u + 0x7FFFu + ((x.u >> 16) & 1u);   // RNE
    return (unsigned short)(r >> 16);
}

__device__ __forceinline__ short8 pack8(floatx4 f0, floatx4 f1) {
    short8 v;
    v[0] = (short)f2bf(f0[0]); v[1] = (short)f2bf(f0[1]);
    v[2] = (short)f2bf(f0[2]); v[3] = (short)f2bf(f0[3]);
    v[4] = (short)f2bf(f1[0]); v[5] = (short)f2bf(f1[1]);
    v[6] = (short)f2bf(f1[2]); v[7] = (short)f2bf(f1[3]);
    return v;
}

// ---------------- K0: Q projection  q[bn,c] = h_x[bn,:].W_Q[c,:] ----------------
__global__ __launch_bounds__(256)
void eama_q(const float* __restrict__ h_x, const float* __restrict__ W_Q,
            float* __restrict__ qbuf)
{
    __shared__ __align__(16) float sHx[16 * HID];   // 16 bn rows
    const int t = threadIdx.x;
    const int b0 = blockIdx.x * 16;
    for (int i = t; i < 16 * HID; i += 256)
        sHx[i] = h_x[b0 * HID + i];
    __syncthreads();
    const int c = t & 127, rh = t >> 7;
    const float* wq = W_Q + c * HID;
    for (int rr = rh; rr < 16; rr += 2) {
        const float* xr = &sHx[rr * HID];
        float acc = 0.f;
        #pragma unroll 8
        for (int e = 0; e < HID; e += 4) {
            floatx4 w4 = *(const floatx4*)(wq + e);
            floatx4 x4 = *(const floatx4*)(xr + e);
            acc += w4[0]*x4[0] + w4[1]*x4[1] + w4[2]*x4[2] + w4[3]*x4[3];
        }
        qbuf[(b0 + rr) * OUTc + c] = acc;
    }
}

// ---------------- K1: per (bn, tile-pair) partial attention ----------------
__global__ __launch_bounds__(256, 4)
void eama_stage1(const float* __restrict__ h_e, const float* __restrict__ h_m,
                 const float* __restrict__ W_K, const float* __restrict__ W_V,
                 const float* __restrict__ qbuf, float* __restrict__ wsP)
{
    __shared__ __align__(16) unsigned short sA[MT * A_LD];   // 4.5 KB
    __shared__ __align__(16) float sK[MT * K_LD];            // 16.9 KB
    __shared__ __align__(16) float sQ[OUTc];
    __shared__ float sSc[MT][4];
    __shared__ float sAt[MT][4];

    const int tid  = threadIdx.x;
    const int lane = tid & 63;
    const int wv   = tid >> 6;
    const int ncol = lane & 15;
    const int q8   = lane >> 4;
    const int bn   = blockIdx.x;
    const int tp   = blockIdx.y;
    const float maskv = h_m[bn];

    if (tid < OUTc) sQ[tid] = qbuf[bn * OUTc + tid];

    // prefetch both h_e tiles into registers (16 KB / block, fully coalesced)
    const float* heb = h_e + ((size_t)bn * Nn + tp * (MT * TPB)) * Ee;
    const int r = tid >> 3, blk = tid & 7;
    floatx4 pf[TPB][2];
    #pragma unroll
    for (int it = 0; it < TPB; ++it) {
        const float* src = heb + (it * MT + r) * Ee + blk * 8;
        pf[it][0] = *(const floatx4*)(src);
        pf[it][1] = *(const floatx4*)(src + 4);
    }

    // B fragments: cols = [W_K rows | W_V rows] (wave wv owns cols wv*64..wv*64+63)
    short8 bfrag[4][2];
    #pragma unroll
    for (int ct = 0; ct < 4; ++ct) {
        const int c = wv * 64 + ct * 16 + ncol;
        const float* row = (c < OUTc) ? (W_K + c * Ee) : (W_V + (c - OUTc) * Ee);
        #pragma unroll
        for (int ks = 0; ks < 2; ++ks) {
            const int k0 = ks * 32 + q8 * 8;
            floatx4 f0 = *(const floatx4*)(row + k0);
            floatx4 f1 = *(const floatx4*)(row + k0 + 4);
            bfrag[ct][ks] = pack8(f0, f1);
        }
    }

    float vs[4], vm[4], asum = 0.f;
    #pragma unroll
    for (int ct = 0; ct < 4; ++ct) { vs[ct] = 0.f; vm[ct] = -3.402823466e38f; }

    for (int it = 0; it < TPB; ++it) {
        // stage A tile (bf16)
        *(short8*)&sA[r * A_LD + blk * 8] = pack8(pf[it][0], pf[it][1]);
        __syncthreads();   // A ready (it=0: also sQ ready)

        // MFMA: this wave's 64 cols of K|V for 32 m-rows
        floatx4 acc[2][4];
        #pragma unroll
        for (int mt = 0; mt < 2; ++mt)
            #pragma unroll
            for (int ct = 0; ct < 4; ++ct)
                acc[mt][ct] = (floatx4){0.f, 0.f, 0.f, 0.f};
        #pragma unroll
        for (int ks = 0; ks < 2; ++ks) {
            short8 a0 = *(const short8*)&sA[(ncol) * A_LD + ks * 32 + q8 * 8];
            short8 a1 = *(const short8*)&sA[(16 + ncol) * A_LD + ks * 32 + q8 * 8];
            #pragma unroll
            for (int ct = 0; ct < 4; ++ct) {
                acc[0][ct] = __builtin_amdgcn_mfma_f32_16x16x32_bf16(a0, bfrag[ct][ks], acc[0][ct], 0, 0, 0);
                acc[1][ct] = __builtin_amdgcn_mfma_f32_16x16x32_bf16(a1, bfrag[ct][ks], acc[1][ct], 0, 0, 0);
            }
        }
        // K half -> LDS (V half stays in registers)
        if (wv < 2) {
            #pragma unroll
            for (int mt = 0; mt < 2; ++mt) {
                const int rowb = mt * 16 + q8 * 4;
                #pragma unroll
                for (int ct = 0; ct < 4; ++ct) {
                    const int col = wv * 64 + ct * 16 + ncol;
                    #pragma unroll
                    for (int rr = 0; rr < 4; ++rr)
                        sK[(rowb + rr) * K_LD + col] = acc[mt][ct][rr];
                }
            }
        }
        __syncthreads();   // K ready

        // scores[m][h] = q[h,:].K[m,h,:] * rsqrt(D)
        if (tid < 128) {
            const int m = tid & 31, h = tid >> 5;
            const float* kr = &sK[m * K_LD + h * Dd];
            const float* qr = &sQ[h * Dd];
            float p = 0.f;
            #pragma unroll
            for (int d = 0; d < Dd; d += 4) {
                floatx4 k4 = *(const floatx4*)(kr + d);
                floatx4 q4 = *(const floatx4*)(qr + d);
                p += k4[0]*q4[0] + k4[1]*q4[1] + k4[2]*q4[2] + k4[3]*q4[3];
            }
            p *= 0.1767766952966369f;
            sSc[m][h] = (maskv != 0.f) ? p : -1e30f;
        }
        __syncthreads();

        // softmax over the 4 HEADS (reference: softmax axis=1)
        if (tid < MT) {
            float s0 = sSc[tid][0], s1 = sSc[tid][1], s2 = sSc[tid][2], s3 = sSc[tid][3];
            float mx = fmaxf(fmaxf(s0, s1), fmaxf(s2, s3));
            float e0 = __expf(s0 - mx), e1 = __expf(s1 - mx);
            float e2 = __expf(s2 - mx), e3 = __expf(s3 - mx);
            float inv = 1.f / (e0 + e1 + e2 + e3);
            sAt[tid][0] = e0 * inv; sAt[tid][1] = e1 * inv;
            sAt[tid][2] = e2 * inv; sAt[tid][3] = e3 * inv;
        }
        __syncthreads();   // attn ready

        // aggregate V directly from MFMA accumulators (waves 2,3)
        if (wv >= 2) {
            #pragma unroll
            for (int ct = 0; ct < 4; ++ct) {
                const int hd = (wv - 2) * 2 + (ct >> 1);
                #pragma unroll
                for (int mt = 0; mt < 2; ++mt) {
                    const int rowb = mt * 16 + q8 * 4;
                    #pragma unroll
                    for (int rr = 0; rr < 4; ++rr) {
                        const float aw = sAt[rowb + rr][hd] * acc[mt][ct][rr];
                        vs[ct] += aw;
                        vm[ct] = fmaxf(vm[ct], aw);
                    }
                }
            }
        }
        if (tid < Hh) {
            #pragma unroll
            for (int m = 0; m < MT; ++m) asum += sAt[m][tid];
        }
        // no barrier needed: sAt's next writer is 3 barriers away; sA's last
        // reader (MFMA) is 3 barriers back.
    }

    // cross-lane reduce over q8 (rows) and write partial record
    const size_t base = ((size_t)bn * NTP + tp) * REC;
    if (wv >= 2) {
        #pragma unroll
        for (int ct = 0; ct < 4; ++ct) {
            vs[ct] += __shfl_xor(vs[ct], 16, 64);
            vs[ct] += __shfl_xor(vs[ct], 32, 64);
            vm[ct] = fmaxf(vm[ct], __shfl_xor(vm[ct], 16, 64));
            vm[ct] = fmaxf(vm[ct], __shfl_xor(vm[ct], 32, 64));
        }
        if (lane < 16) {
            #pragma unroll
            for (int ct = 0; ct < 4; ++ct) {
                const int cv = (wv - 2) * 64 + ct * 16 + ncol;
                wsP[base + cv]        = vs[ct];
                wsP[base + OUTc + cv] = vm[ct];
            }
        }
    }
    if (tid < Hh) wsP[base + 2 * OUTc + tid] = asum;
}

// ---------------- K2: reduce partials, build multi, out = multi @ W_R^T ----------------
__global__ __launch_bounds__(128)
void eama_stage2(const float* __restrict__ wsP, const float* __restrict__ W_R,
                 float* __restrict__ out)
{
    __shared__ __align__(16) float sM[REC];
    __shared__ float sAs[Hh];
    const int tid = threadIdx.x;
    const int bn  = blockIdx.x;
    const size_t base = (size_t)bn * NTP * REC;

    float vsum = 0.f, vmax = -3.402823466e38f;
    #pragma unroll
    for (int tp = 0; tp < NTP; ++tp) {
        vsum += wsP[base + tp * REC + tid];
        vmax = fmaxf(vmax, wsP[base + tp * REC + OUTc + tid]);
    }
    if (tid < Hh) {
        float a = 1e-8f;
        #pragma unroll
        for (int tp = 0; tp < NTP; ++tp) a += wsP[base + tp * REC + 2 * OUTc + tid];
        sAs[tid] = a;
    }
    __syncthreads();
    {
        const int h = tid >> 5, d = tid & 31;
        sM[h * 65 + d]      = vsum / sAs[h];
        sM[h * 65 + 33 + d] = vmax;
        if (tid < Hh) sM[tid * 65 + 32] = sAs[tid];
    }
    __syncthreads();
    {
        const float* wr = W_R + tid * AGG;
        float acc = 0.f;
        #pragma unroll 5
        for (int j = 0; j < AGG; j += 4) {
            floatx4 w4 = *(const floatx4*)(wr + j);
            floatx4 m4 = *(const floatx4*)(&sM[j]);
            acc += w4[0]*m4[0] + w4[1]*m4[1] + w4[2]*m4[2] + w4[3]*m4[3];
        }
        out[bn * OUTc + tid] = acc;
    }
}

extern "C" void kernel_launch(void* const* d_in, const int* in_sizes, int n_in,
                              void* d_out, int out_size, void* d_ws, size_t ws_size,
                              hipStream_t stream) {
    const float* h_x = (const float*)d_in[0];
    const float* h_e = (const float*)d_in[1];
    const float* h_m = (const float*)d_in[2];
    const float* W_Q = (const float*)d_in[3];
    const float* W_K = (const float*)d_in[4];
    const float* W_V = (const float*)d_in[5];
    const float* W_R = (const float*)d_in[6];
    float* out  = (float*)d_out;
    float* wsP  = (float*)d_ws;                         // 1024*4*264 floats
    float* qbuf = wsP + (size_t)Bb * Nn * NTP * REC;    // +1024*128 floats (~4.85 MB total)

    eama_q<<<dim3(Bb * Nn / 16), dim3(256), 0, stream>>>(h_x, W_Q, qbuf);
    eama_stage1<<<dim3(Bb * Nn, NTP), dim3(256), 0, stream>>>(h_e, h_m, W_K, W_V, qbuf, wsP);
    eama_stage2<<<dim3(Bb * Nn), dim3(128), 0, stream>>>(wsP, W_R, out);
}

// Round 3
// 139.788 us; speedup vs baseline: 1.4171x; 1.4171x over previous
//
#include <hip/hip_runtime.h>

// Problem constants (EdgeAwareMultiHeadAttention)
constexpr int Bb   = 4;
constexpr int Nn   = 256;
constexpr int HID  = 256;
constexpr int Ee   = 64;
constexpr int Hh   = 4;
constexpr int OUTc = 128;   // HID/2
constexpr int Dd   = 32;    // OUT/H
constexpr int AGG  = 260;   // H*(2D+1)

constexpr int MT    = 32;   // m-tile rows (stage1)
constexpr int TPB   = 2;    // tiles per block (64 m-rows per block)
constexpr int NTP   = Nn / (MT * TPB);   // 4 tile-pairs per bn
constexpr int A_LD  = 72;   // bf16 row stride for stage1 A tile
constexpr int K_LD  = 132;  // fp32 row stride for K tile (pad 128->132)
constexpr int REC   = 264;  // ws record stride (260 padded to 16B multiple)
constexpr int QA_LD = 264;  // bf16 row stride for Q-proj A tile (K=256, pad +8)

// ws layout (floats)
constexpr size_t WS_PART  = 0;                                   // 1024*4*264
constexpr size_t WS_QBUF  = (size_t)Bb * Nn * NTP * REC;         // +1024*128
constexpr size_t WS_WRT   = WS_QBUF + (size_t)Bb * Nn * OUTc;    // +260*128
constexpr size_t WS_FRAG  = WS_WRT + (size_t)AGG * OUTc;         // +8192 floats (16384 shorts)

typedef __attribute__((ext_vector_type(8))) short short8;
typedef __attribute__((ext_vector_type(4))) float floatx4;

__device__ __forceinline__ unsigned short f2bf(float f) {
    union { float f; unsigned u; } x; x.f = f;
    unsigned r = x.u + 0x7FFFu + ((x.u >> 16) & 1u);   // RNE
    return (unsigned short)(r >> 16);
}

__device__ __forceinline__ short8 pack8(floatx4 f0, floatx4 f1) {
    short8 v;
    v[0] = (short)f2bf(f0[0]); v[1] = (short)f2bf(f0[1]);
    v[2] = (short)f2bf(f0[2]); v[3] = (short)f2bf(f0[3]);
    v[4] = (short)f2bf(f1[0]); v[5] = (short)f2bf(f1[1]);
    v[6] = (short)f2bf(f1[2]); v[7] = (short)f2bf(f1[3]);
    return v;
}

// ---------------- K_pre: weight prepack + Q projection (block-range split) ----------------
// blocks 0..7     : pack W_K|W_V -> bf16 B-fragments in stage1 lane order
// blocks 8..137   : transpose W_R -> W_RT[j][c]
// blocks 138..201 : Q projection via MFMA, 16 bn-rows per block
__global__ __launch_bounds__(256)
void eama_pre(const float* __restrict__ h_x, const float* __restrict__ W_Q,
              const float* __restrict__ W_K, const float* __restrict__ W_V,
              const float* __restrict__ W_R,
              unsigned short* __restrict__ wfragKV, float* __restrict__ W_RT,
              float* __restrict__ qbuf)
{
    __shared__ __align__(16) unsigned short sA[16 * QA_LD];   // 8.25 KB (Q-proj path only)
    const int tid = threadIdx.x;
    const int bid = blockIdx.x;

    if (bid < 8) {
        // ---- pack K|V fragments: entry e = ((wv*4+ct)*2+ks)*64 + lane ----
        const int e    = bid * 256 + tid;          // 0..2047
        const int lane = e & 63;
        const int ks   = (e >> 6) & 1;
        const int ct   = (e >> 7) & 3;
        const int wv   = (e >> 9) & 3;
        const int ncol = lane & 15, q8 = lane >> 4;
        const int c = wv * 64 + ct * 16 + ncol;
        const float* row = (c < OUTc) ? (W_K + c * Ee) : (W_V + (c - OUTc) * Ee);
        const int k0 = ks * 32 + q8 * 8;
        floatx4 f0 = *(const floatx4*)(row + k0);
        floatx4 f1 = *(const floatx4*)(row + k0 + 4);
        *(short8*)(wfragKV + (size_t)e * 8) = pack8(f0, f1);
    } else if (bid < 138) {
        // ---- transpose W_R [128x260] -> W_RT [260x128] (coalesced writes) ----
        const int i = (bid - 8) * 256 + tid;       // 0..33279
        if (i < AGG * OUTc) {
            const int c = i & 127, j = i >> 7;
            W_RT[j * OUTc + c] = W_R[c * AGG + j];
        }
    } else {
        // ---- Q projection: rows b0..b0+15, q = h_x @ W_Q^T via bf16 MFMA ----
        const int b0   = (bid - 138) * 16;
        const int lane = tid & 63;
        const int wv   = tid >> 6;
        const int ncol = lane & 15, q8 = lane >> 4;

        // W_Q fragments for this wave's 32 cols (small one-time gather)
        short8 bq[2][8];
        #pragma unroll
        for (int ct = 0; ct < 2; ++ct) {
            const int c = wv * 32 + ct * 16 + ncol;
            const float* row = W_Q + c * HID;
            #pragma unroll
            for (int ks = 0; ks < 8; ++ks) {
                const int k0 = ks * 32 + q8 * 8;
                floatx4 f0 = *(const floatx4*)(row + k0);
                floatx4 f1 = *(const floatx4*)(row + k0 + 4);
                bq[ct][ks] = pack8(f0, f1);
            }
        }
        // stage A tile: 16 rows x 256 k (bf16)
        #pragma unroll
        for (int i = 0; i < 2; ++i) {
            const int idx = tid + i * 256;         // 0..511
            const int r = idx >> 5, blk = idx & 31;
            const float* src = h_x + (size_t)(b0 + r) * HID + blk * 8;
            floatx4 f0 = *(const floatx4*)(src);
            floatx4 f1 = *(const floatx4*)(src + 4);
            *(short8*)&sA[r * QA_LD + blk * 8] = pack8(f0, f1);
        }
        __syncthreads();
        floatx4 acc[2] = {(floatx4){0,0,0,0}, (floatx4){0,0,0,0}};
        #pragma unroll
        for (int ks = 0; ks < 8; ++ks) {
            short8 a = *(const short8*)&sA[ncol * QA_LD + ks * 32 + q8 * 8];
            acc[0] = __builtin_amdgcn_mfma_f32_16x16x32_bf16(a, bq[0][ks], acc[0], 0, 0, 0);
            acc[1] = __builtin_amdgcn_mfma_f32_16x16x32_bf16(a, bq[1][ks], acc[1], 0, 0, 0);
        }
        #pragma unroll
        for (int ct = 0; ct < 2; ++ct)
            #pragma unroll
            for (int rr = 0; rr < 4; ++rr)
                qbuf[(size_t)(b0 + q8 * 4 + rr) * OUTc + wv * 32 + ct * 16 + ncol] = acc[ct][rr];
    }
}

// ---------------- K1: per (bn, tile-pair) partial attention ----------------
__global__ __launch_bounds__(256, 4)
void eama_stage1(const float* __restrict__ h_e, const float* __restrict__ h_m,
                 const unsigned short* __restrict__ wfragKV,
                 const float* __restrict__ qbuf, float* __restrict__ wsP)
{
    __shared__ __align__(16) unsigned short sA[MT * A_LD];   // 4.5 KB
    __shared__ __align__(16) float sK[MT * K_LD];            // 16.9 KB
    __shared__ __align__(16) float sQ[OUTc];
    __shared__ float sSc[MT][4];
    __shared__ float sAt[MT][4];

    const int tid  = threadIdx.x;
    const int lane = tid & 63;
    const int wv   = tid >> 6;
    const int ncol = lane & 15;
    const int q8   = lane >> 4;
    const int bn   = blockIdx.x;
    const int tp   = blockIdx.y;
    const float maskv = h_m[bn];

    if (tid < OUTc) sQ[tid] = qbuf[bn * OUTc + tid];

    // prefetch both h_e tiles into registers (16 KB / block, fully coalesced)
    const float* heb = h_e + ((size_t)bn * Nn + tp * (MT * TPB)) * Ee;
    const int r = tid >> 3, blk = tid & 7;
    floatx4 pf[TPB][2];
    #pragma unroll
    for (int it = 0; it < TPB; ++it) {
        const float* src = heb + (it * MT + r) * Ee + blk * 8;
        pf[it][0] = *(const floatx4*)(src);
        pf[it][1] = *(const floatx4*)(src + 4);
    }

    // B fragments from packed buffer — fully coalesced (lane-contiguous 16B)
    short8 bfrag[4][2];
    #pragma unroll
    for (int ct = 0; ct < 4; ++ct)
        #pragma unroll
        for (int ks = 0; ks < 2; ++ks) {
            const int e = ((wv * 4 + ct) * 2 + ks) * 64 + lane;
            bfrag[ct][ks] = *(const short8*)(wfragKV + (size_t)e * 8);
        }

    float vs[4], vm[4], asum = 0.f;
    #pragma unroll
    for (int ct = 0; ct < 4; ++ct) { vs[ct] = 0.f; vm[ct] = -3.402823466e38f; }

    for (int it = 0; it < TPB; ++it) {
        // stage A tile (bf16)
        *(short8*)&sA[r * A_LD + blk * 8] = pack8(pf[it][0], pf[it][1]);
        __syncthreads();   // A ready (it=0: also sQ ready)

        // MFMA: this wave's 64 cols of K|V for 32 m-rows
        floatx4 acc[2][4];
        #pragma unroll
        for (int mt = 0; mt < 2; ++mt)
            #pragma unroll
            for (int ct = 0; ct < 4; ++ct)
                acc[mt][ct] = (floatx4){0.f, 0.f, 0.f, 0.f};
        #pragma unroll
        for (int ks = 0; ks < 2; ++ks) {
            short8 a0 = *(const short8*)&sA[(ncol) * A_LD + ks * 32 + q8 * 8];
            short8 a1 = *(const short8*)&sA[(16 + ncol) * A_LD + ks * 32 + q8 * 8];
            #pragma unroll
            for (int ct = 0; ct < 4; ++ct) {
                acc[0][ct] = __builtin_amdgcn_mfma_f32_16x16x32_bf16(a0, bfrag[ct][ks], acc[0][ct], 0, 0, 0);
                acc[1][ct] = __builtin_amdgcn_mfma_f32_16x16x32_bf16(a1, bfrag[ct][ks], acc[1][ct], 0, 0, 0);
            }
        }
        // K half -> LDS (V half stays in registers)
        if (wv < 2) {
            #pragma unroll
            for (int mt = 0; mt < 2; ++mt) {
                const int rowb = mt * 16 + q8 * 4;
                #pragma unroll
                for (int ct = 0; ct < 4; ++ct) {
                    const int col = wv * 64 + ct * 16 + ncol;
                    #pragma unroll
                    for (int rr = 0; rr < 4; ++rr)
                        sK[(rowb + rr) * K_LD + col] = acc[mt][ct][rr];
                }
            }
        }
        __syncthreads();   // K ready

        // scores[m][h] = q[h,:].K[m,h,:] * rsqrt(D)
        if (tid < 128) {
            const int m = tid & 31, h = tid >> 5;
            const float* kr = &sK[m * K_LD + h * Dd];
            const float* qr = &sQ[h * Dd];
            float p = 0.f;
            #pragma unroll
            for (int d = 0; d < Dd; d += 4) {
                floatx4 k4 = *(const floatx4*)(kr + d);
                floatx4 q4 = *(const floatx4*)(qr + d);
                p += k4[0]*q4[0] + k4[1]*q4[1] + k4[2]*q4[2] + k4[3]*q4[3];
            }
            p *= 0.1767766952966369f;
            sSc[m][h] = (maskv != 0.f) ? p : -1e30f;
        }
        __syncthreads();

        // softmax over the 4 HEADS (reference: softmax axis=1)
        if (tid < MT) {
            float s0 = sSc[tid][0], s1 = sSc[tid][1], s2 = sSc[tid][2], s3 = sSc[tid][3];
            float mx = fmaxf(fmaxf(s0, s1), fmaxf(s2, s3));
            float e0 = __expf(s0 - mx), e1 = __expf(s1 - mx);
            float e2 = __expf(s2 - mx), e3 = __expf(s3 - mx);
            float inv = 1.f / (e0 + e1 + e2 + e3);
            sAt[tid][0] = e0 * inv; sAt[tid][1] = e1 * inv;
            sAt[tid][2] = e2 * inv; sAt[tid][3] = e3 * inv;
        }
        __syncthreads();   // attn ready

        // aggregate V directly from MFMA accumulators (waves 2,3)
        if (wv >= 2) {
            #pragma unroll
            for (int ct = 0; ct < 4; ++ct) {
                const int hd = (wv - 2) * 2 + (ct >> 1);
                #pragma unroll
                for (int mt = 0; mt < 2; ++mt) {
                    const int rowb = mt * 16 + q8 * 4;
                    #pragma unroll
                    for (int rr = 0; rr < 4; ++rr) {
                        const float aw = sAt[rowb + rr][hd] * acc[mt][ct][rr];
                        vs[ct] += aw;
                        vm[ct] = fmaxf(vm[ct], aw);
                    }
                }
            }
        }
        if (tid < Hh) {
            #pragma unroll
            for (int m = 0; m < MT; ++m) asum += sAt[m][tid];
        }
        // no barrier needed: sAt's next writer is 3 barriers away; sA's last
        // reader (MFMA) is 3 barriers back.
    }

    // cross-lane reduce over q8 (rows) and write partial record
    const size_t base = ((size_t)bn * NTP + tp) * REC;
    if (wv >= 2) {
        #pragma unroll
        for (int ct = 0; ct < 4; ++ct) {
            vs[ct] += __shfl_xor(vs[ct], 16, 64);
            vs[ct] += __shfl_xor(vs[ct], 32, 64);
            vm[ct] = fmaxf(vm[ct], __shfl_xor(vm[ct], 16, 64));
            vm[ct] = fmaxf(vm[ct], __shfl_xor(vm[ct], 32, 64));
        }
        if (lane < 16) {
            #pragma unroll
            for (int ct = 0; ct < 4; ++ct) {
                const int cv = (wv - 2) * 64 + ct * 16 + ncol;
                wsP[base + cv]        = vs[ct];
                wsP[base + OUTc + cv] = vm[ct];
            }
        }
    }
    if (tid < Hh) wsP[base + 2 * OUTc + tid] = asum;
}

// ---------------- K2: reduce partials, build multi, out = multi @ W_R^T ----------------
__global__ __launch_bounds__(128)
void eama_stage2(const float* __restrict__ wsP, const float* __restrict__ W_RT,
                 float* __restrict__ out)
{
    __shared__ __align__(16) float sM[REC];
    __shared__ float sAs[Hh];
    const int tid = threadIdx.x;
    const int bn  = blockIdx.x;
    const size_t base = (size_t)bn * NTP * REC;

    float vsum = 0.f, vmax = -3.402823466e38f;
    #pragma unroll
    for (int tp = 0; tp < NTP; ++tp) {
        vsum += wsP[base + tp * REC + tid];
        vmax = fmaxf(vmax, wsP[base + tp * REC + OUTc + tid]);
    }
    if (tid < Hh) {
        float a = 1e-8f;
        #pragma unroll
        for (int tp = 0; tp < NTP; ++tp) a += wsP[base + tp * REC + 2 * OUTc + tid];
        sAs[tid] = a;
    }
    __syncthreads();
    {
        const int h = tid >> 5, d = tid & 31;
        sM[h * 65 + d]      = vsum / sAs[h];
        sM[h * 65 + 33 + d] = vmax;
        if (tid < Hh) sM[tid * 65 + 32] = sAs[tid];
    }
    __syncthreads();
    {
        // coalesced GEMV over transposed W_R: lanes read consecutive cols
        float acc = 0.f;
        #pragma unroll 4
        for (int j = 0; j < AGG; ++j)
            acc = fmaf(sM[j], W_RT[j * OUTc + tid], acc);
        out[bn * OUTc + tid] = acc;
    }
}

extern "C" void kernel_launch(void* const* d_in, const int* in_sizes, int n_in,
                              void* d_out, int out_size, void* d_ws, size_t ws_size,
                              hipStream_t stream) {
    const float* h_x = (const float*)d_in[0];
    const float* h_e = (const float*)d_in[1];
    const float* h_m = (const float*)d_in[2];
    const float* W_Q = (const float*)d_in[3];
    const float* W_K = (const float*)d_in[4];
    const float* W_V = (const float*)d_in[5];
    const float* W_R = (const float*)d_in[6];
    float* out = (float*)d_out;

    float* ws            = (float*)d_ws;
    float* wsP           = ws + WS_PART;
    float* qbuf          = ws + WS_QBUF;
    float* W_RT          = ws + WS_WRT;
    unsigned short* wfKV = (unsigned short*)(ws + WS_FRAG);

    eama_pre<<<dim3(138 + Bb * Nn / 16), dim3(256), 0, stream>>>(
        h_x, W_Q, W_K, W_V, W_R, wfKV, W_RT, qbuf);
    eama_stage1<<<dim3(Bb * Nn, NTP), dim3(256), 0, stream>>>(h_e, h_m, wfKV, qbuf, wsP);
    eama_stage2<<<dim3(Bb * Nn), dim3(128), 0, stream>>>(wsP, W_RT, out);
}

// Round 4
// 129.921 us; speedup vs baseline: 1.5247x; 1.0759x over previous
//
#include <hip/hip_runtime.h>

// Problem constants (EdgeAwareMultiHeadAttention)
constexpr int Bb   = 4;
constexpr int Nn   = 256;
constexpr int HID  = 256;
constexpr int Ee   = 64;
constexpr int Hh   = 4;
constexpr int OUTc = 128;   // HID/2
constexpr int Dd   = 32;    // OUT/H
constexpr int AGG  = 260;   // H*(2D+1)
constexpr int REC  = 264;   // ws record stride
constexpr int QA_LD = 264;  // bf16 row stride for Q-proj A tile

// ws layout (float offsets)
constexpr size_t WS_PART  = 0;                                    // 1024*2*264 partial records
constexpr size_t WS_QBUF  = WS_PART + (size_t)Bb * Nn * 2 * REC;  // 1024*128 q
constexpr size_t WS_WRT   = WS_QBUF + (size_t)Bb * Nn * OUTc;     // 260*128 W_R^T
constexpr size_t WS_FRAGV = WS_WRT + (size_t)AGG * OUTc;          // 1024 frag entries (4096 floats)
constexpr size_t WS_UFRAG = WS_FRAGV + 4096;                      // 1024*2*64 entries (524288 floats)

typedef __attribute__((ext_vector_type(8))) short short8;
typedef __attribute__((ext_vector_type(4))) float floatx4;

__device__ __forceinline__ unsigned short f2bf(float f) {
    union { float f; unsigned u; } x; x.f = f;
    unsigned r = x.u + 0x7FFFu + ((x.u >> 16) & 1u);   // RNE
    return (unsigned short)(r >> 16);
}

__device__ __forceinline__ short8 pack8(floatx4 f0, floatx4 f1) {
    short8 v;
    v[0] = (short)f2bf(f0[0]); v[1] = (short)f2bf(f0[1]);
    v[2] = (short)f2bf(f0[2]); v[3] = (short)f2bf(f0[3]);
    v[4] = (short)f2bf(f1[0]); v[5] = (short)f2bf(f1[1]);
    v[6] = (short)f2bf(f1[2]); v[7] = (short)f2bf(f1[3]);
    return v;
}

// ---------------- K_pre1: V-fragment pack + W_R transpose + Q projection ----------------
// blocks 0..3     : pack W_V -> bf16 B-fragments (stage1 lane order)
// blocks 4..133   : transpose W_R -> W_RT[j][c]
// blocks 134..197 : Q projection via MFMA, 16 bn-rows per block
__global__ __launch_bounds__(256)
void eama_pre(const float* __restrict__ h_x, const float* __restrict__ W_Q,
              const float* __restrict__ W_V, const float* __restrict__ W_R,
              unsigned short* __restrict__ wfragV, float* __restrict__ W_RT,
              float* __restrict__ qbuf)
{
    __shared__ __align__(16) unsigned short sA[16 * QA_LD];   // Q-proj path only
    const int tid = threadIdx.x;
    const int bid = blockIdx.x;

    if (bid < 4) {
        // entry e = (ct*2+ks)*64 + lane ; value = W_V[ct*16+ncol][ks*32+q8*8+j]
        const int e    = bid * 256 + tid;          // 0..1023
        const int lane = e & 63;
        const int ks   = (e >> 6) & 1;
        const int ct   = e >> 7;                   // 0..7
        const int ncol = lane & 15, q8 = lane >> 4;
        const float* row = W_V + (ct * 16 + ncol) * Ee;
        const int k0 = ks * 32 + q8 * 8;
        floatx4 f0 = *(const floatx4*)(row + k0);
        floatx4 f1 = *(const floatx4*)(row + k0 + 4);
        *(short8*)(wfragV + (size_t)e * 8) = pack8(f0, f1);
    } else if (bid < 134) {
        const int i = (bid - 4) * 256 + tid;       // 0..33279
        if (i < AGG * OUTc) {
            const int c = i & 127, j = i >> 7;
            W_RT[j * OUTc + c] = W_R[c * AGG + j];
        }
    } else {
        // Q projection: rows b0..b0+15, q = h_x @ W_Q^T via bf16 MFMA
        const int b0   = (bid - 134) * 16;
        const int lane = tid & 63;
        const int wv   = tid >> 6;
        const int ncol = lane & 15, q8 = lane >> 4;

        short8 bq[2][8];
        #pragma unroll
        for (int ct = 0; ct < 2; ++ct) {
            const int c = wv * 32 + ct * 16 + ncol;
            const float* row = W_Q + c * HID;
            #pragma unroll
            for (int ks = 0; ks < 8; ++ks) {
                const int k0 = ks * 32 + q8 * 8;
                floatx4 f0 = *(const floatx4*)(row + k0);
                floatx4 f1 = *(const floatx4*)(row + k0 + 4);
                bq[ct][ks] = pack8(f0, f1);
            }
        }
        #pragma unroll
        for (int i = 0; i < 2; ++i) {
            const int idx = tid + i * 256;         // 0..511
            const int r = idx >> 5, blk = idx & 31;
            const float* src = h_x + (size_t)(b0 + r) * HID + blk * 8;
            floatx4 f0 = *(const floatx4*)(src);
            floatx4 f1 = *(const floatx4*)(src + 4);
            *(short8*)&sA[r * QA_LD + blk * 8] = pack8(f0, f1);
        }
        __syncthreads();
        floatx4 acc[2] = {(floatx4){0,0,0,0}, (floatx4){0,0,0,0}};
        #pragma unroll
        for (int ks = 0; ks < 8; ++ks) {
            short8 a = *(const short8*)&sA[ncol * QA_LD + ks * 32 + q8 * 8];
            acc[0] = __builtin_amdgcn_mfma_f32_16x16x32_bf16(a, bq[0][ks], acc[0], 0, 0, 0);
            acc[1] = __builtin_amdgcn_mfma_f32_16x16x32_bf16(a, bq[1][ks], acc[1], 0, 0, 0);
        }
        #pragma unroll
        for (int ct = 0; ct < 2; ++ct)
            #pragma unroll
            for (int rr = 0; rr < 4; ++rr)
                qbuf[(size_t)(b0 + q8 * 4 + rr) * OUTc + wv * 32 + ct * 16 + ncol] = acc[ct][rr];
    }
}

// ---------------- K_pre2: u[h,e] = sum_d q[h*32+d]*W_K[h*32+d,e] * rsqrt(D), packed as B-frags ----------------
__global__ __launch_bounds__(256)
void eama_u(const float* __restrict__ qbuf, const float* __restrict__ W_K,
            unsigned short* __restrict__ ufrag)
{
    __shared__ float sq[OUTc];
    __shared__ __align__(16) float sU[Hh][Ee];
    const int tid = threadIdx.x;
    const int bn  = blockIdx.x;
    if (tid < OUTc) sq[tid] = qbuf[bn * OUTc + tid];
    __syncthreads();
    {
        const int h = tid >> 6, e = tid & 63;
        float a0 = 0.f, a1 = 0.f;
        #pragma unroll
        for (int d = 0; d < Dd; d += 2) {
            a0 = fmaf(sq[h * Dd + d],     W_K[(h * Dd + d) * Ee + e],     a0);
            a1 = fmaf(sq[h * Dd + d + 1], W_K[(h * Dd + d + 1) * Ee + e], a1);
        }
        sU[h][e] = (a0 + a1) * 0.1767766952966369f;   // fold 1/sqrt(32)
    }
    __syncthreads();
    if (tid < 128) {
        const int ks = tid >> 6, l = tid & 63;
        const int nc = l & 15, q8 = l >> 4;
        short8 v = {0,0,0,0,0,0,0,0};
        if (nc < Hh) {
            const float* u = &sU[nc][ks * 32 + q8 * 8];
            floatx4 f0 = *(const floatx4*)u;
            floatx4 f1 = *(const floatx4*)(u + 4);
            v = pack8(f0, f1);
        }
        *(short8*)(ufrag + ((size_t)(bn * 2 + ks) * 64 + l) * 8) = v;
    }
}

// ---------------- K1: barrier-free fused V-projection + head-softmax + aggregation ----------------
// grid (1024, 2); wave w of block (bn,hf) owns rows hf*128 + w*32 + it*16 + (0..15)
__global__ __launch_bounds__(256, 2)
void eama_stage1(const float* __restrict__ h_e, const float* __restrict__ h_m,
                 const unsigned short* __restrict__ wfragV,
                 const unsigned short* __restrict__ ufrag,
                 float* __restrict__ wsP)
{
    __shared__ float sVS[4][OUTc];
    __shared__ float sVM[4][OUTc];
    __shared__ float sAS[4][Hh];

    const int tid  = threadIdx.x;
    const int lane = tid & 63;
    const int w    = tid >> 6;
    const int ncol = lane & 15;
    const int q8   = lane >> 4;
    const int bn   = blockIdx.x;
    const int hf   = blockIdx.y;
    const float maskv = h_m[bn];

    // B fragments (coalesced 16B/lane): 8 V col-tiles x 2 k-steps + score tile (u)
    short8 bfV[8][2];
    #pragma unroll
    for (int ct = 0; ct < 8; ++ct)
        #pragma unroll
        for (int ks = 0; ks < 2; ++ks)
            bfV[ct][ks] = *(const short8*)(wfragV + ((size_t)(ct * 2 + ks) * 64 + lane) * 8);
    short8 bu[2];
    bu[0] = *(const short8*)(ufrag + ((size_t)(bn * 2 + 0) * 64 + lane) * 8);
    bu[1] = *(const short8*)(ufrag + ((size_t)(bn * 2 + 1) * 64 + lane) * 8);

    float vs[8], vm[8], asum = 0.f;
    #pragma unroll
    for (int ct = 0; ct < 8; ++ct) { vs[ct] = 0.f; vm[ct] = -3.402823466e38f; }

    const float* heb = h_e + (size_t)bn * Nn * Ee;

    #pragma unroll
    for (int it = 0; it < 2; ++it) {
        const int m0 = hf * 128 + w * 32 + it * 16;
        // A fragments straight from global: lane = row (m0+ncol), k = ks*32+q8*8+j
        const float* ar = heb + (size_t)(m0 + ncol) * Ee;
        short8 af[2];
        #pragma unroll
        for (int ks = 0; ks < 2; ++ks) {
            floatx4 f0 = *(const floatx4*)(ar + ks * 32 + q8 * 8);
            floatx4 f1 = *(const floatx4*)(ar + ks * 32 + q8 * 8 + 4);
            af[ks] = pack8(f0, f1);
        }
        floatx4 accV[8], accS = (floatx4){0,0,0,0};
        #pragma unroll
        for (int ct = 0; ct < 8; ++ct) accV[ct] = (floatx4){0,0,0,0};
        #pragma unroll
        for (int ks = 0; ks < 2; ++ks) {
            #pragma unroll
            for (int ct = 0; ct < 8; ++ct)
                accV[ct] = __builtin_amdgcn_mfma_f32_16x16x32_bf16(af[ks], bfV[ct][ks], accV[ct], 0, 0, 0);
            accS = __builtin_amdgcn_mfma_f32_16x16x32_bf16(af[ks], bu[ks], accS, 0, 0, 0);
        }
        // head-softmax: S[row=q8*4+r][h=ncol] for ncol<4; heads are lanes differing in bits 0-1
        float a[4];
        #pragma unroll
        for (int r = 0; r < 4; ++r) {
            float s = (maskv != 0.f) ? accS[r] : -1e30f;
            float m1 = fmaxf(s, __shfl_xor(s, 1, 64));
            m1 = fmaxf(m1, __shfl_xor(m1, 2, 64));
            float e = __expf(s - m1);
            float t = e + __shfl_xor(e, 1, 64);
            t += __shfl_xor(t, 2, 64);
            a[r] = e / t;
        }
        asum += a[0] + a[1] + a[2] + a[3];          // valid in lanes ncol<4 (h = ncol)
        // broadcast attn to V lanes and accumulate sum/max over rows
        #pragma unroll
        for (int h = 0; h < Hh; ++h) {
            const int src = (lane & 48) | h;        // same q8 group, lane holding head h
            float aw0 = __shfl(a[0], src, 64);
            float aw1 = __shfl(a[1], src, 64);
            float aw2 = __shfl(a[2], src, 64);
            float aw3 = __shfl(a[3], src, 64);
            #pragma unroll
            for (int g = 0; g < 2; ++g) {
                const int ct = h * 2 + g;           // V cols ct*16+ncol belong to head ct>>1
                float p0 = aw0 * accV[ct][0];
                float p1 = aw1 * accV[ct][1];
                float p2 = aw2 * accV[ct][2];
                float p3 = aw3 * accV[ct][3];
                vs[ct] += (p0 + p1) + (p2 + p3);
                vm[ct] = fmaxf(vm[ct], fmaxf(fmaxf(p0, p1), fmaxf(p2, p3)));
            }
        }
    }

    // reduce over q8 row-groups (lanes xor 16,32)
    #pragma unroll
    for (int ct = 0; ct < 8; ++ct) {
        vs[ct] += __shfl_xor(vs[ct], 16, 64);
        vs[ct] += __shfl_xor(vs[ct], 32, 64);
        vm[ct] = fmaxf(vm[ct], __shfl_xor(vm[ct], 16, 64));
        vm[ct] = fmaxf(vm[ct], __shfl_xor(vm[ct], 32, 64));
    }
    asum += __shfl_xor(asum, 16, 64);
    asum += __shfl_xor(asum, 32, 64);

    // block merge (single barrier in the whole kernel)
    if (lane < 16) {
        #pragma unroll
        for (int ct = 0; ct < 8; ++ct) {
            sVS[w][ct * 16 + lane] = vs[ct];
            sVM[w][ct * 16 + lane] = vm[ct];
        }
    }
    if (lane < Hh) sAS[w][lane] = asum;
    __syncthreads();
    if (tid < OUTc) {
        const size_t base = (size_t)(bn * 2 + hf) * REC;
        float vsum = (sVS[0][tid] + sVS[1][tid]) + (sVS[2][tid] + sVS[3][tid]);
        float vmax = fmaxf(fmaxf(sVS[0][tid], sVS[0][tid]), 0.f); // placeholder avoided below
        vmax = fmaxf(fmaxf(sVM[0][tid], sVM[1][tid]), fmaxf(sVM[2][tid], sVM[3][tid]));
        wsP[base + tid]        = vsum;
        wsP[base + OUTc + tid] = vmax;
        if (tid < Hh)
            wsP[base + 2 * OUTc + tid] =
                (sAS[0][tid] + sAS[1][tid]) + (sAS[2][tid] + sAS[3][tid]);
    }
}

// ---------------- K2: reduce 2 partials, build multi, out = multi @ W_R^T ----------------
__global__ __launch_bounds__(128)
void eama_stage2(const float* __restrict__ wsP, const float* __restrict__ W_RT,
                 float* __restrict__ out)
{
    __shared__ __align__(16) float sM[REC];
    __shared__ float sAs[Hh];
    const int tid = threadIdx.x;
    const int bn  = blockIdx.x;
    const size_t base = (size_t)bn * 2 * REC;

    float vsum = wsP[base + tid] + wsP[base + REC + tid];
    float vmax = fmaxf(wsP[base + OUTc + tid], wsP[base + REC + OUTc + tid]);
    if (tid < Hh)
        sAs[tid] = wsP[base + 2 * OUTc + tid] + wsP[base + REC + 2 * OUTc + tid] + 1e-8f;
    __syncthreads();
    {
        const int h = tid >> 5, d = tid & 31;
        sM[h * 65 + d]      = vsum / sAs[h];
        sM[h * 65 + 33 + d] = vmax;
        if (tid < Hh) sM[tid * 65 + 32] = sAs[tid];
    }
    __syncthreads();
    {
        float a0 = 0.f, a1 = 0.f, a2 = 0.f, a3 = 0.f;
        #pragma unroll 5
        for (int j = 0; j < AGG; j += 4) {
            a0 = fmaf(sM[j],     W_RT[(j)     * OUTc + tid], a0);
            a1 = fmaf(sM[j + 1], W_RT[(j + 1) * OUTc + tid], a1);
            a2 = fmaf(sM[j + 2], W_RT[(j + 2) * OUTc + tid], a2);
            a3 = fmaf(sM[j + 3], W_RT[(j + 3) * OUTc + tid], a3);
        }
        out[bn * OUTc + tid] = (a0 + a1) + (a2 + a3);
    }
}

extern "C" void kernel_launch(void* const* d_in, const int* in_sizes, int n_in,
                              void* d_out, int out_size, void* d_ws, size_t ws_size,
                              hipStream_t stream) {
    const float* h_x = (const float*)d_in[0];
    const float* h_e = (const float*)d_in[1];
    const float* h_m = (const float*)d_in[2];
    const float* W_Q = (const float*)d_in[3];
    const float* W_K = (const float*)d_in[4];
    const float* W_V = (const float*)d_in[5];
    const float* W_R = (const float*)d_in[6];
    float* out = (float*)d_out;

    float* ws            = (float*)d_ws;
    float* wsP           = ws + WS_PART;
    float* qbuf          = ws + WS_QBUF;
    float* W_RT          = ws + WS_WRT;
    unsigned short* wfV  = (unsigned short*)(ws + WS_FRAGV);
    unsigned short* ufr  = (unsigned short*)(ws + WS_UFRAG);

    eama_pre<<<dim3(198), dim3(256), 0, stream>>>(h_x, W_Q, W_V, W_R, wfV, W_RT, qbuf);
    eama_u<<<dim3(Bb * Nn), dim3(256), 0, stream>>>(qbuf, W_K, ufr);
    eama_stage1<<<dim3(Bb * Nn, 2), dim3(256), 0, stream>>>(h_e, h_m, wfV, ufr, wsP);
    eama_stage2<<<dim3(Bb * Nn), dim3(128), 0, stream>>>(wsP, W_RT, out);
}